// Round 13
// baseline (445.143 us; speedup 1.0000x reference)
//
#include <hip/hip_runtime.h>

#define NCH 6
#define NX 32
#define PLANE 1024
#define NCELL (NX * PLANE)
#define STEP_STRIDE (NCH * NCELL)
#define NTHREADS 1024
#define NBLOCKS 128
#define RB 2
#define NE 960                      // extended t+1 cells: 3 planes x 10 rows x 32
#define NT3 1152                    // LDS t-slab: 3 planes x 12 rows x 32

#define RING_WORDS ((size_t)RB * 3 * NCELL)
#define F_DONE 0

typedef unsigned long long u64;

__device__ __forceinline__ u64 ld64(const u64* p) {
    return __hip_atomic_load(p, __ATOMIC_RELAXED, __HIP_MEMORY_SCOPE_SYSTEM);
}
__device__ __forceinline__ void st64(u64* p, u64 v) {
    __hip_atomic_store(p, v, __ATOMIC_RELAXED, __HIP_MEMORY_SCOPE_SYSTEM);
}
__device__ __forceinline__ int ldi(const int* p) {
    return __hip_atomic_load(p, __ATOMIC_RELAXED, __HIP_MEMORY_SCOPE_SYSTEM);
}
__device__ __forceinline__ void sti(int* p, int v) {
    __hip_atomic_store(p, v, __ATOMIC_RELAXED, __HIP_MEMORY_SCOPE_SYSTEM);
}
__device__ __forceinline__ u64 pack2p(float a, float b, unsigned P) {
    const u64 w = ((u64)__float_as_uint(b) << 32) | __float_as_uint(a);
    return P ? (w | 0x8000000080000000ULL) : w;
}
__device__ __forceinline__ bool tagok(u64 w, unsigned P) {
    return (((unsigned)(w >> 63)) == P) & ((((unsigned)w) >> 31) == P);
}
__device__ __forceinline__ void unpack2(u64 w, float* d0, float* d1) {
    *d0 = __uint_as_float((unsigned)w & 0x7fffffffu);
    *d1 = __uint_as_float((unsigned)(w >> 32) & 0x7fffffffu);
}

// k=2 temporal blocking: one tagged-ring exchange per TWO CA steps.
// Block = (x-plane, 8-row stripe); 1024 threads cover 960 extended cells
// (planes x-1..x+1, rows ys-1..ys+8). Superstep ss (t=2ss):
//   poll ring for phi_t: LDS 3-plane slab (1152 cells, duty A/B) + private
//   x+-2 reads by outer-plane threads; stage1: every extended thread computes
//   phi_{t+1} AT ITS OWN CELL with its own 36 D-coeffs (halo recompute);
//   stage2: own threads (256) compute phi_{t+2} from the LDS t+1 buffer,
//   publish tagged (superstep granularity), write history t+1 and t+2.
// Sign-bit parity protocol (R10-proven) at superstep granularity: mutual
// deps bound skew<=1 -> (slot=ss&1, P=(ss>>1)&1) disambiguates; poison is
// sign=1 -> bootstrap-safe. Abort is step-stamped via F_DONE (dn).
__global__ void __launch_bounds__(NTHREADS, 1)
BEMNA_V7_2_PhaseSpace_44117904064519_kernel(
    const float* __restrict__ D,
    const int* __restrict__ sx_p, const int* __restrict__ sy_p,
    const int* __restrict__ sz_p, const int* __restrict__ ex_p,
    const int* __restrict__ ey_p, const int* __restrict__ ez_p,
    const int* __restrict__ maxit_p,
    float* __restrict__ out,
    u64* __restrict__ ring,
    int* __restrict__ flags)
{
    __shared__ float Tb[NCH][NT3];   // phi_t slab: planes x-1..x+1, rows ys-2..ys+9
    __shared__ float Eb[NCH][NE];    // phi_{t+1}: planes x-1..x+1, rows ys-1..ys+8
    __shared__ int lds_dn;
    volatile int* vdn = &lds_dn;

    const int tid = (int)threadIdx.x;
    const int bx  = (int)blockIdx.x;
    const int x   = bx >> 2;
    const int ys  = (bx & 3) << 3;

    const int sx = *sx_p, sy = *sy_p, sz = *sz_p;
    const int ex = *ex_p, ey = *ey_p, ez_ = *ez_p;
    const int maxit = *maxit_p;
    const int seedc = (sx << 10) | (sy << 5) | sz;
    const int targc = (ex << 10) | (ey << 5) | ez_;

    // always-valid own-block cell for dummy reads (record exists every epoch)
    const int anchor = (x << 10) + (ys << 5) + (tid & 31);

    // ---- T-slab read duties (A: slot=tid, B: slot=tid+1024) ----
    int cTA = anchor, slA = 0; bool inA = false;
    if (tid < NT3) {
        const int dp = tid / 384, rem = tid - dp * 384;
        const int r2 = rem >> 5, zz = rem & 31;
        const int gx = x - 1 + dp, gy = ys - 2 + r2;
        slA = tid;
        if (gx >= 0 && gx < 32 && gy >= 0 && gy < 32) { inA = true; cTA = (gx << 10) + (gy << 5) + zz; }
    }
    int cTB = anchor, slB = 0; bool inB = false;
    if (tid < NT3 - 1024) {
        const int slot = tid + 1024;
        const int dp = slot / 384, rem = slot - dp * 384;
        const int r2 = rem >> 5, zz = rem & 31;
        const int gx = x - 1 + dp, gy = ys - 2 + r2;
        slB = slot;
        if (gx >= 0 && gx < 32 && gy >= 0 && gy < 32) { inB = true; cTB = (gx << 10) + (gy << 5) + zz; }
    }

    // ---- extended-cell (E) duty ----
    const bool eact = (tid < NE);
    int dx = 0, ry = 0, ez = tid & 31, xe = x, ye = ys;
    bool ein = false;
    int celle = anchor;
    if (eact) {
        dx = tid / 320; const int rem = tid - dx * 320; ry = rem >> 5; ez = rem & 31;
        xe = x - 1 + dx; ye = ys - 1 + ry;
        ein = (xe >= 0 && xe < 32 && ye >= 0 && ye < 32);
        if (ein) celle = (xe << 10) + (ye << 5) + ez;
    }
    const bool own = ein && (dx == 1) && (ry >= 1) && (ry <= 8);
    const bool is_seed   = own && (celle == seedc);
    const bool is_target = own && (celle == targc);

    // private outward-x read (dx==0 -> x-2, dx==2 -> x+2); anchor if OOB
    int cP = anchor;
    if (eact && ein && dx == 0 && x - 2 >= 0)  cP = ((x - 2) << 10) + (ye << 5) + ez;
    if (eact && ein && dx == 2 && x + 2 <= 31) cP = ((x + 2) << 10) + (ye << 5) + ez;

    // D coefficients for THIS thread's cell (same regs serve t+1 and t+2)
    const int  nbg[NCH] = { celle - PLANE, celle + PLANE, celle - 32, celle + 32, celle - 1, celle + 1 };
    const bool okn[NCH] = { ein && xe >= 1, ein && xe <= 30, ein && ye >= 1,
                            ein && ye <= 30, ein && ez >= 1, ein && ez <= 30 };
    float dreg[NCH][NCH];
#pragma unroll
    for (int o = 0; o < NCH; ++o)
#pragma unroll
        for (int i = 0; i < NCH; ++i)
            dreg[o][i] = okn[o] ? D[(size_t)(o * NCH + i) * NCELL + nbg[o]] + 0.95f : 0.0f;

    // T-slab LDS indices for stage-1 (clamped; dreg=0 masks invalid uses)
    const int ts3  = (dx * 12 + ry + 1) * 32 + ez;
    const int tpa0 = (ts3 - 384 >= 0) ? ts3 - 384 : 0;        // x-1 (dx>=1)
    const int tpa1 = (ts3 + 384 < NT3) ? ts3 + 384 : NT3 - 1; // x+1 (dx<=1)
    const int tp2 = ts3 - 32, tp3 = ts3 + 32;
    const int tp4 = (ez >= 1) ? ts3 - 1 : ts3, tp5 = (ez <= 30) ? ts3 + 1 : ts3;
    // E LDS indices for stage-2 (own threads; all in-bounds for tid in [352,608))
    const int en0 = tid - 320, en1 = tid + 320, en2 = tid - 32, en3 = tid + 32;
    const int en4 = (ez >= 1) ? tid - 1 : tid, en5 = (ez <= 30) ? tid + 1 : tid;

    // ---- init: zero LDS; publish epoch-ss 0; history slice 0 ----
    for (int k = tid; k < NCH * NT3; k += NTHREADS) ((float*)Tb)[k] = 0.0f;
    for (int k = tid; k < NCH * NE;  k += NTHREADS) ((float*)Eb)[k] = 0.0f;
    if (tid == 0) lds_dn = -1;
    if (own) {
        const float iv = is_seed ? 1.0f : 0.0f;
        const u64 p = pack2p(iv, iv, 0);
        st64(&ring[0 * NCELL + celle], p);
        st64(&ring[1 * NCELL + celle], p);
        st64(&ring[2 * NCELL + celle], p);
#pragma unroll
        for (int o = 0; o < NCH; ++o) out[o * NCELL + celle] = iv;
    }
    __syncthreads();

    int tripped = 0;
    for (int ss = 0; 2 * ss + 1 <= maxit - 1; ++ss) {
        const u64* r0 = ring + (size_t)(ss & 1) * 3 * NCELL;
        const u64* r1 = r0 + NCELL;
        const u64* r2 = r1 + NCELL;
        const unsigned P = (unsigned)((ss >> 1) & 1);

        // ---- poll phi_{2ss}: 9 batched loads/round (R10 discipline) ----
        u64 a0, a1, a2, b0, b1, b2, p0, p1, p2;
        for (;;) {
            a0 = ld64(r0 + cTA); a1 = ld64(r1 + cTA); a2 = ld64(r2 + cTA);
            b0 = ld64(r0 + cTB); b1 = ld64(r1 + cTB); b2 = ld64(r2 + cTB);
            p0 = ld64(r0 + cP);  p1 = ld64(r1 + cP);  p2 = ld64(r2 + cP);
            int dnv = -1;
            if ((tid & 63) == 0) dnv = ldi(&flags[F_DONE]);
            if (dnv >= 0) *vdn = dnv;
            const bool okr = tagok(a0, P) & tagok(a1, P) & tagok(a2, P)
                           & tagok(b0, P) & tagok(b1, P) & tagok(b2, P)
                           & tagok(p0, P) & tagok(p1, P) & tagok(p2, P);
            const int d = *vdn;
            if (d >= 0 && 2 * ss + 1 > d) break;       // abort: data moot
            if (__ballot(okr) == ~0ull) break;
            __builtin_amdgcn_s_sleep(1);
        }
        // stash slab data (skip if this superstep aborts uniformly below)
        if (inA) {
            unpack2(a0, &Tb[0][slA], &Tb[1][slA]);
            unpack2(a1, &Tb[2][slA], &Tb[3][slA]);
            unpack2(a2, &Tb[4][slA], &Tb[5][slA]);
        }
        if (inB) {
            unpack2(b0, &Tb[0][slB], &Tb[1][slB]);
            unpack2(b1, &Tb[2][slB], &Tb[3][slB]);
            unpack2(b2, &Tb[4][slB], &Tb[5][slB]);
        }
        float pX[NCH];
        unpack2(p0, &pX[0], &pX[1]); unpack2(p1, &pX[2], &pX[3]); unpack2(p2, &pX[4], &pX[5]);

        __syncthreads();                               // sync1: slab complete, vdn settled
        { const int d = *vdn; if (d >= 0 && 2 * ss + 1 > d) break; }  // uniform abort

        // ---- stage 1: phi_{2ss+1} at every extended cell ----
        float v1[NCH] = {0, 0, 0, 0, 0, 0};
        if (eact) {
            float s0 = 0.f, s1 = 0.f, s2 = 0.f, s3 = 0.f, s4 = 0.f, s5 = 0.f;
#pragma unroll
            for (int i = 0; i < NCH; ++i) {
                const float xi0 = (dx == 0) ? pX[i] : Tb[i][tpa0];
                const float xi1 = (dx == 2) ? pX[i] : Tb[i][tpa1];
                s0 = fmaf(dreg[0][i], xi0, s0);
                s1 = fmaf(dreg[1][i], xi1, s1);
                s2 = fmaf(dreg[2][i], Tb[i][tp2], s2);
                s3 = fmaf(dreg[3][i], Tb[i][tp3], s3);
                s4 = fmaf(dreg[4][i], Tb[i][tp4], s4);
                s5 = fmaf(dreg[5][i], Tb[i][tp5], s5);
            }
            v1[0] = fminf(fmaxf(s0, 0.f), 1.f);
            v1[1] = fminf(fmaxf(s1, 0.f), 1.f);
            v1[2] = fminf(fmaxf(s2, 0.f), 1.f);
            v1[3] = fminf(fmaxf(s3, 0.f), 1.f);
            v1[4] = fminf(fmaxf(s4, 0.f), 1.f);
            v1[5] = fminf(fmaxf(s5, 0.f), 1.f);
        }
        if (own) {                                     // history slice 2ss+1
            float* op = out + (size_t)(2 * ss + 1) * STEP_STRIDE + celle;
#pragma unroll
            for (int o = 0; o < NCH; ++o) op[o * NCELL] = v1[o];
            if (is_target && !tripped &&
                (v1[0] + v1[1] + v1[2] + v1[3] + v1[4] + v1[5] > 0.01f)) {
                sti(&flags[F_DONE], 2 * ss + 1);
                tripped = 1;
            }
        }
        if (eact) {
#pragma unroll
            for (int i = 0; i < NCH; ++i) Eb[i][tid] = v1[i];
        }
        __syncthreads();                               // sync2: Eb complete

        // ---- stage 2: phi_{2ss+2} at own cells; publish + history ----
        if (own) {
            float s0 = 0.f, s1 = 0.f, s2 = 0.f, s3 = 0.f, s4 = 0.f, s5 = 0.f;
#pragma unroll
            for (int i = 0; i < NCH; ++i) {
                s0 = fmaf(dreg[0][i], Eb[i][en0], s0);
                s1 = fmaf(dreg[1][i], Eb[i][en1], s1);
                s2 = fmaf(dreg[2][i], Eb[i][en2], s2);
                s3 = fmaf(dreg[3][i], Eb[i][en3], s3);
                s4 = fmaf(dreg[4][i], Eb[i][en4], s4);
                s5 = fmaf(dreg[5][i], Eb[i][en5], s5);
            }
            float v2[NCH];
            v2[0] = fminf(fmaxf(s0, 0.f), 1.f);
            v2[1] = fminf(fmaxf(s1, 0.f), 1.f);
            v2[2] = fminf(fmaxf(s2, 0.f), 1.f);
            v2[3] = fminf(fmaxf(s3, 0.f), 1.f);
            v2[4] = fminf(fmaxf(s4, 0.f), 1.f);
            v2[5] = fminf(fmaxf(s5, 0.f), 1.f);
            if (is_target && !tripped &&
                (v2[0] + v2[1] + v2[2] + v2[3] + v2[4] + v2[5] > 0.01f)) {
                sti(&flags[F_DONE], 2 * ss + 2);
                tripped = 1;
            }
            const unsigned P1 = (unsigned)(((ss + 1) >> 1) & 1);
            u64* w = ring + (size_t)((ss + 1) & 1) * 3 * NCELL;
            st64(w + 0 * NCELL + celle, pack2p(v2[0], v2[1], P1));
            st64(w + 1 * NCELL + celle, pack2p(v2[2], v2[3], P1));
            st64(w + 2 * NCELL + celle, pack2p(v2[4], v2[5], P1));
            if (2 * ss + 2 <= maxit - 1) {             // history slice 2ss+2
                float* op = out + (size_t)(2 * ss + 2) * STEP_STRIDE + celle;
#pragma unroll
                for (int o = 0; o < NCH; ++o) op[o * NCELL] = v2[o];
            }
        }
        // no sync3 needed: next-superstep Tb/Eb writes happen only after that
        // superstep's poll-exit + sync1, and all waves passed sync2 here.
    }
}

// 2D read-once/write-many fill: grid (192, 8). Chunk c copies slices
// tf+1+c, tf+1+c+8, ... from out[tf]. Uses the full chip's write BW.
__global__ void fill_kernel(const int* __restrict__ flags,
                            float4* __restrict__ out,
                            int total4)
{
    const int s4 = STEP_STRIDE / 4;
    const int maxit = total4 / s4;
    const int ds = flags[F_DONE];
    const int tf = (ds >= 1 && ds <= maxit - 1) ? ds : maxit - 1;
    const int idx = (int)blockIdx.x * (int)blockDim.x + (int)threadIdx.x;
    const float4 v = out[(size_t)tf * s4 + idx];
    for (int t = tf + 1 + (int)blockIdx.y; t < maxit; t += (int)gridDim.y)
        out[(size_t)t * s4 + idx] = v;
}

extern "C" void kernel_launch(void* const* d_in, const int* in_sizes, int n_in,
                              void* d_out, int out_size, void* d_ws, size_t ws_size,
                              hipStream_t stream)
{
    const float* D   = (const float*)d_in[0];
    const int* sx    = (const int*)d_in[1];
    const int* sy    = (const int*)d_in[2];
    const int* sz    = (const int*)d_in[3];
    const int* ex    = (const int*)d_in[4];
    const int* ey    = (const int*)d_in[5];
    const int* ez    = (const int*)d_in[6];
    const int* maxit = (const int*)d_in[7];
    float* out = (float*)d_out;

    u64* ring  = (u64*)d_ws;                   // 2 x 3 x 32768 x 8B = 1.6 MB
    int* flags = (int*)(ring + RING_WORDS);

    // 128 blocks x 1024 threads (extended stripes), k=2 temporal blocking.
    // Plain launch; co-residency by capacity (128 blocks, 1 block/CU).
    BEMNA_V7_2_PhaseSpace_44117904064519_kernel<<<dim3(NBLOCKS), dim3(NTHREADS), 0, stream>>>(
        D, sx, sy, sz, ex, ey, ez, maxit, out, ring, flags);

    const int total4 = out_size / 4;
    fill_kernel<<<dim3((STEP_STRIDE / 4) / 256, 8), dim3(256), 0, stream>>>(
        flags, (float4*)out, total4);
}